// Round 14
// baseline (275.498 us; speedup 1.0000x reference)
//
#include <hip/hip_runtime.h>
#include <hip/hip_bf16.h>

#define N_NODES 50000
#define NE      800000
#define DIN     128
#define DHID    128
#define DOUT    64
#define BN_EPS  1e-5f
#define SLOT    64      // padded CSR row capacity; P(Poisson(16)>64)~3e-18, guarded
#define NBUK    98      // dest buckets of 512 nodes (c>>9)
#define BCAP    8704    // bucket capacity: lambda=8163, +6 sigma, guarded
#define EPB     2048    // edges per block, binA
#define PHB     6250    // prop1 blocks per phase (50000/8)
#define LDW     132     // padded W1T row (66 dwords, %32==2 -> <=2-way LDS aliasing)
#define LDW2    132

typedef __hip_bfloat16 bf16;
typedef short bf16x8 __attribute__((ext_vector_type(8)));
typedef float f32x4 __attribute__((ext_vector_type(4)));

__device__ __forceinline__ float ldf(const void* p, int i, int isbf) {
    if (isbf) return __bfloat162float(((const bf16*)p)[i]);
    return ((const float*)p)[i];
}
__device__ __forceinline__ unsigned short f2b(float f) {
    bf16 h = __float2bfloat16(f);
    return *(unsigned short*)&h;
}
__device__ __forceinline__ float2 up2(unsigned int u) {
    return make_float2(__uint_as_float(u << 16), __uint_as_float(u & 0xffff0000u));
}
__device__ __forceinline__ unsigned int pk2(float a, float b) {
    return ((unsigned int)f2b(a)) | (((unsigned int)f2b(b)) << 16);
}

#define DETECT_ISBF(W1raw, tid, sdet, isbf_out)                                   \
    if ((tid) == 0) sdet = 0;                                                     \
    __syncthreads();                                                              \
    {                                                                             \
        unsigned int u_ = ((unsigned int)((const unsigned short*)(W1raw))[tid]) << 16; \
        float f_ = fabsf(__uint_as_float(u_));                                    \
        if (!isnan(f_) && !isinf(f_) && f_ > 1e4f) atomicOr(&sdet, 1);            \
    }                                                                             \
    __syncthreads();                                                              \
    const int isbf_out = !sdet;

// ---------- binA: decode + LDS counting-sort by dest bucket + chunked coalesced write ----------
__global__ __launch_bounds__(256) void k_binA(const void* eiraw, int* __restrict__ gcnt,
                                              int* __restrict__ counts, unsigned int* __restrict__ bpk) {
    __shared__ int hist[128], lofs[128], cur[128], gbase[128];
    __shared__ unsigned int stg[EPB];
    __shared__ int sdet;
    int tid = threadIdx.x;
    for (int i = blockIdx.x * 256 + tid; i < N_NODES; i += gridDim.x * 256) counts[i] = 0;
    if (tid == 0) sdet = 0;
    if (tid < 128) hist[tid] = 0;
    __syncthreads();
    if (tid < 64 && ((const unsigned int*)eiraw)[2 * tid + 1] != 0u) atomicOr(&sdet, 1);
    __syncthreads();
    const int isll = !sdet;

    int e0 = blockIdx.x * EPB;
    int nE = NE - e0; if (nE > EPB) nE = EPB;
    int r[8], c[8];
    #pragma unroll
    for (int q = 0; q < 8; ++q) {
        int li = q * 256 + tid;
        if (li < nE) {
            int e = e0 + li;
            if (isll) { r[q] = (int)((const long long*)eiraw)[e]; c[q] = (int)((const long long*)eiraw)[NE + e]; }
            else      { r[q] = ((const int*)eiraw)[e];            c[q] = ((const int*)eiraw)[NE + e]; }
            atomicAdd(&hist[c[q] >> 9], 1);
        } else r[q] = -1;
    }
    __syncthreads();
    if (tid == 0) {
        int acc = 0;
        for (int b = 0; b < NBUK; ++b) { lofs[b] = acc; acc += hist[b]; }
    }
    __syncthreads();
    if (tid < NBUK) { gbase[tid] = atomicAdd(&gcnt[tid], hist[tid]); cur[tid] = lofs[tid]; }
    __syncthreads();
    #pragma unroll
    for (int q = 0; q < 8; ++q) {
        if (r[q] >= 0) {
            int b = c[q] >> 9;
            int p = atomicAdd(&cur[b], 1);
            stg[p] = ((unsigned int)b << 25) | ((unsigned int)(c[q] & 511) << 16) | (unsigned int)r[q];
        }
    }
    __syncthreads();
    for (int i = tid; i < nE; i += 256) {
        unsigned int v = stg[i];
        int b = v >> 25;
        int pos = gbase[b] + (i - lofs[b]);
        if (pos < BCAP) bpk[b * BCAP + pos] = v;
    }
}

// ---------- binB: per-bucket scatter into padded CSR, 4 blocks/bucket ----------
__global__ __launch_bounds__(256) void k_binB(const unsigned int* __restrict__ bpk, const int* __restrict__ gcnt,
                                              int* __restrict__ counts, int* __restrict__ ej) {
    int b = blockIdx.x >> 2;
    int part = blockIdx.x & 3;
    int m = gcnt[b]; if (m > BCAP) m = BCAP;
    const unsigned int* src = bpk + b * BCAP;
    for (int i = part * 256 + threadIdx.x; i < m; i += 1024) {
        unsigned int v = src[i];
        int c = (b << 9) | ((v >> 16) & 511);
        int s = v & 0xffff;
        int k = atomicAdd(&counts[c], 1);
        if (k < SLOT) ej[c * SLOT + k] = s;
    }
}

// ---------- GEMM1 (MFMA): g1 = bf16(dis[m] * (x @ W1 + b1)), dis from counts ----------
__global__ __launch_bounds__(256) void k_gemm1_mfma(const void* __restrict__ x, const void* __restrict__ W1,
                                                    const void* __restrict__ b1, const int* __restrict__ counts,
                                                    unsigned short* __restrict__ g1) {
    __shared__ unsigned short wt[128 * LDW];
    __shared__ int sdet;
    int tid = threadIdx.x;
    DETECT_ISBF(W1, tid, sdet, isbf)

    #pragma unroll 4
    for (int i = 0; i < 64; ++i) {
        int idx = i * 256 + tid;
        int k = idx >> 7, n = idx & 127;
        wt[n * LDW + k] = isbf ? ((const unsigned short*)W1)[idx]
                               : f2b(((const float*)W1)[idx]);
    }
    __syncthreads();

    int lane = tid & 63;
    int wave = tid >> 6;
    int m0 = blockIdx.x * 64 + wave * 16;
    int lm = lane & 15;
    int quad = lane >> 4;

    bf16x8 a[4];
    int arow = m0 + lm;
    int arow_c = arow < N_NODES ? arow : 0;
    if (isbf) {
        const unsigned short* xb = (const unsigned short*)x;
        #pragma unroll
        for (int q = 0; q < 4; ++q)
            a[q] = *(const bf16x8*)(xb + arow_c * DIN + q * 32 + quad * 8);
    } else {
        const float* xf = (const float*)x;
        #pragma unroll
        for (int q = 0; q < 4; ++q) {
            bf16x8 t;
            #pragma unroll
            for (int j = 0; j < 8; ++j)
                t[j] = (short)f2b(xf[arow_c * DIN + q * 32 + quad * 8 + j]);
            a[q] = t;
        }
    }

    float dsc[4];
    #pragma unroll
    for (int r = 0; r < 4; ++r) {
        int grow = m0 + quad * 4 + r;
        dsc[r] = (grow < N_NODES) ? rsqrtf((float)(counts[grow] + 1)) : 0.f;
    }

    #pragma unroll
    for (int nt = 0; nt < 8; ++nt) {
        int n0 = nt * 16;
        f32x4 acc = {0.f, 0.f, 0.f, 0.f};
        #pragma unroll
        for (int q = 0; q < 4; ++q) {
            bf16x8 b = *(const bf16x8*)(wt + (n0 + lm) * LDW + q * 32 + quad * 8);
            acc = __builtin_amdgcn_mfma_f32_16x16x32_bf16(a[q], b, acc, 0, 0, 0);
        }
        float bias = ldf(b1, n0 + lm, isbf);
        #pragma unroll
        for (int r = 0; r < 4; ++r) {
            int grow = m0 + quad * 4 + r;
            if (grow < N_NODES)
                g1[grow * DHID + n0 + lm] = f2b(dsc[r] * (acc[r] + bias));
        }
    }
}

// ---------- propagate 1: 2-phase feature split (working set 6.4MB/phase vs 4MB L2/XCD) ----------
// phase 0 = dwords 0..31 (feats 0..63), phase 1 = dwords 32..63. Half-wave (32 lanes) per node,
// 8 nodes/block. agg1[c] = bf16( dis[c] * (g1[c] + sum g1[src]) ), g1 pre-scaled by dis[src].
__global__ __launch_bounds__(256) void k_prop1(const int* __restrict__ counts, const int* __restrict__ ej,
                                               const unsigned int* __restrict__ g1p,   // [N][64] dwords
                                               unsigned int* __restrict__ agg1p) {
    int tid = threadIdx.x;
    int phase = blockIdx.x >= PHB;
    int base = (phase ? blockIdx.x - PHB : blockIdx.x) * 8;
    int n = base + (tid >> 5);
    if (n >= N_NODES) return;
    int doff = (phase << 5) + (tid & 31);
    int cnt = counts[n];
    int t = cnt < SLOT ? cnt : SLOT;
    const int* ejn = ej + (size_t)n * SLOT;
    float2 v = up2(g1p[(size_t)n * 64 + doff]);
    float ax0 = v.x, ay0 = v.y, ax1 = 0.f, ay1 = 0.f;
    float ax2 = 0.f, ay2 = 0.f, ax3 = 0.f, ay3 = 0.f;
    int j = 0;
    for (; j + 8 <= t; j += 8) {
        int e0 = ejn[j], e1 = ejn[j + 1], e2 = ejn[j + 2], e3 = ejn[j + 3];
        int e4 = ejn[j + 4], e5 = ejn[j + 5], e6 = ejn[j + 6], e7 = ejn[j + 7];
        unsigned int g0 = g1p[(size_t)e0 * 64 + doff];
        unsigned int g1_ = g1p[(size_t)e1 * 64 + doff];
        unsigned int g2 = g1p[(size_t)e2 * 64 + doff];
        unsigned int g3 = g1p[(size_t)e3 * 64 + doff];
        unsigned int g4 = g1p[(size_t)e4 * 64 + doff];
        unsigned int g5 = g1p[(size_t)e5 * 64 + doff];
        unsigned int g6 = g1p[(size_t)e6 * 64 + doff];
        unsigned int g7 = g1p[(size_t)e7 * 64 + doff];
        float2 f0 = up2(g0), f1 = up2(g1_), f2 = up2(g2), f3 = up2(g3);
        float2 f4 = up2(g4), f5 = up2(g5), f6 = up2(g6), f7 = up2(g7);
        ax0 += f0.x; ay0 += f0.y; ax1 += f1.x; ay1 += f1.y;
        ax2 += f2.x; ay2 += f2.y; ax3 += f3.x; ay3 += f3.y;
        ax0 += f4.x; ay0 += f4.y; ax1 += f5.x; ay1 += f5.y;
        ax2 += f6.x; ay2 += f6.y; ax3 += f7.x; ay3 += f7.y;
    }
    for (; j < t; ++j) {
        float2 f = up2(g1p[(size_t)ejn[j] * 64 + doff]);
        ax0 += f.x; ay0 += f.y;
    }
    float dv = rsqrtf((float)(cnt + 1));
    float ax = dv * ((ax0 + ax1) + (ax2 + ax3));
    float ay = dv * ((ay0 + ay1) + (ay2 + ay3));
    agg1p[(size_t)n * 64 + doff] = pk2(ax, ay);
}

// ---------- BN statistics over bf16 agg1 ----------
__global__ __launch_bounds__(256) void k_stats(const unsigned int* __restrict__ agg1p, float* __restrict__ stats) {
    int tid = threadIdx.x;
    const int total = N_NODES * 64;
    float sx = 0.f, sy = 0.f, qx = 0.f, qy = 0.f;
    for (int idx = blockIdx.x * 256 + tid; idx < total; idx += gridDim.x * 256) {
        float2 v = up2(agg1p[idx]);
        sx += v.x; sy += v.y; qx += v.x * v.x; qy += v.y * v.y;
    }
    __shared__ float lsx[256], lsy[256], lqx[256], lqy[256];
    lsx[tid] = sx; lsy[tid] = sy; lqx[tid] = qx; lqy[tid] = qy;
    __syncthreads();
    if (tid < 64) {
        float tsx = lsx[tid] + lsx[tid + 64] + lsx[tid + 128] + lsx[tid + 192];
        float tsy = lsy[tid] + lsy[tid + 64] + lsy[tid + 128] + lsy[tid + 192];
        float tqx = lqx[tid] + lqx[tid + 64] + lqx[tid + 128] + lqx[tid + 192];
        float tqy = lqy[tid] + lqy[tid + 64] + lqy[tid + 128] + lqy[tid + 192];
        atomicAdd(&stats[2 * tid], tsx);
        atomicAdd(&stats[2 * tid + 1], tsy);
        atomicAdd(&stats[128 + 2 * tid], tqx);
        atomicAdd(&stats[128 + 2 * tid + 1], tqy);
    }
}

// ---------- GEMM2 (MFMA), BN finalize in preamble, BN+ReLU on A, dis-scale out ----------
__global__ __launch_bounds__(256) void k_gemm2_mfma(const unsigned int* __restrict__ agg1p,
                                                    const float* __restrict__ stats,
                                                    const void* __restrict__ gamma, const void* __restrict__ beta,
                                                    const void* __restrict__ W2, const void* __restrict__ b2,
                                                    const void* __restrict__ W1, const int* __restrict__ counts,
                                                    unsigned short* __restrict__ g2) {
    __shared__ unsigned short w2t[64 * LDW2];
    __shared__ float sc[128], sh[128];
    __shared__ int sdet;
    int tid = threadIdx.x;
    DETECT_ISBF(W1, tid, sdet, isbf)

    #pragma unroll 4
    for (int i = 0; i < 32; ++i) {
        int idx = i * 256 + tid;
        int k = idx >> 6, n = idx & 63;
        w2t[n * LDW2 + k] = isbf ? ((const unsigned short*)W2)[idx]
                                 : f2b(((const float*)W2)[idx]);
    }
    if (tid < 128) {
        const float invn = 1.0f / (float)N_NODES;
        float mu = stats[tid] * invn;
        float var = stats[128 + tid] * invn - mu * mu;
        float rs = rsqrtf(var + BN_EPS);
        float g = ldf(gamma, tid, isbf);
        sc[tid] = rs * g;
        sh[tid] = ldf(beta, tid, isbf) - mu * rs * g;
    }
    __syncthreads();

    int lane = tid & 63;
    int wave = tid >> 6;
    int m0 = blockIdx.x * 64 + wave * 16;
    int lm = lane & 15;
    int quad = lane >> 4;

    int arow = m0 + lm;
    int arow_c = arow < N_NODES ? arow : 0;
    bf16x8 a[4];
    #pragma unroll
    for (int q = 0; q < 4; ++q) {
        uint4 gv = *(const uint4*)(agg1p + (size_t)arow_c * 64 + q * 16 + quad * 4);
        int kb = q * 32 + quad * 8;
        float2 f0 = up2(gv.x), f1 = up2(gv.y), f2 = up2(gv.z), f3 = up2(gv.w);
        float e0 = f0.x * sc[kb + 0] + sh[kb + 0];
        float e1 = f0.y * sc[kb + 1] + sh[kb + 1];
        float e2 = f1.x * sc[kb + 2] + sh[kb + 2];
        float e3 = f1.y * sc[kb + 3] + sh[kb + 3];
        float e4 = f2.x * sc[kb + 4] + sh[kb + 4];
        float e5 = f2.y * sc[kb + 5] + sh[kb + 5];
        float e6 = f3.x * sc[kb + 6] + sh[kb + 6];
        float e7 = f3.y * sc[kb + 7] + sh[kb + 7];
        bf16x8 t;
        t[0] = (short)f2b(e0 > 0.f ? e0 : 0.f);
        t[1] = (short)f2b(e1 > 0.f ? e1 : 0.f);
        t[2] = (short)f2b(e2 > 0.f ? e2 : 0.f);
        t[3] = (short)f2b(e3 > 0.f ? e3 : 0.f);
        t[4] = (short)f2b(e4 > 0.f ? e4 : 0.f);
        t[5] = (short)f2b(e5 > 0.f ? e5 : 0.f);
        t[6] = (short)f2b(e6 > 0.f ? e6 : 0.f);
        t[7] = (short)f2b(e7 > 0.f ? e7 : 0.f);
        a[q] = t;
    }

    float dsc[4];
    #pragma unroll
    for (int r = 0; r < 4; ++r) {
        int grow = m0 + quad * 4 + r;
        dsc[r] = (grow < N_NODES) ? rsqrtf((float)(counts[grow] + 1)) : 0.f;
    }

    #pragma unroll
    for (int nt = 0; nt < 4; ++nt) {
        int n0 = nt * 16;
        f32x4 acc = {0.f, 0.f, 0.f, 0.f};
        #pragma unroll
        for (int q = 0; q < 4; ++q) {
            bf16x8 b = *(const bf16x8*)(w2t + (n0 + lm) * LDW2 + q * 32 + quad * 8);
            acc = __builtin_amdgcn_mfma_f32_16x16x32_bf16(a[q], b, acc, 0, 0, 0);
        }
        float bias = ldf(b2, n0 + lm, isbf);
        #pragma unroll
        for (int r = 0; r < 4; ++r) {
            int grow = m0 + quad * 4 + r;
            if (grow < N_NODES)
                g2[grow * DOUT + n0 + lm] = f2b(dsc[r] * (acc[r] + bias));
        }
    }
}

// ---------- propagate 2 + log_softmax: 32 lanes/node, 2 feats/lane, 8-edge ILP ----------
__global__ __launch_bounds__(256) void k_prop2_lsm(const int* __restrict__ counts, const int* __restrict__ ej,
                                                   const unsigned int* __restrict__ g2p,   // [N][32] dwords
                                                   const void* __restrict__ W1, void* __restrict__ out) {
    __shared__ int sdet;
    int tid = threadIdx.x;
    DETECT_ISBF(W1, tid, sdet, isbf)

    int n = blockIdx.x * 8 + (tid >> 5);
    if (n >= N_NODES) return;
    int lane = tid & 31;
    int cnt = counts[n];
    int t = cnt < SLOT ? cnt : SLOT;
    const int* ejn = ej + (size_t)n * SLOT;
    float2 v = up2(g2p[(size_t)n * 32 + lane]);
    float ax0 = v.x, ay0 = v.y, ax1 = 0.f, ay1 = 0.f;
    float ax2 = 0.f, ay2 = 0.f, ax3 = 0.f, ay3 = 0.f;
    int j = 0;
    for (; j + 8 <= t; j += 8) {
        int e0 = ejn[j], e1 = ejn[j + 1], e2 = ejn[j + 2], e3 = ejn[j + 3];
        int e4 = ejn[j + 4], e5 = ejn[j + 5], e6 = ejn[j + 6], e7 = ejn[j + 7];
        unsigned int g0 = g2p[(size_t)e0 * 32 + lane];
        unsigned int g1_ = g2p[(size_t)e1 * 32 + lane];
        unsigned int g2 = g2p[(size_t)e2 * 32 + lane];
        unsigned int g3 = g2p[(size_t)e3 * 32 + lane];
        unsigned int g4 = g2p[(size_t)e4 * 32 + lane];
        unsigned int g5 = g2p[(size_t)e5 * 32 + lane];
        unsigned int g6 = g2p[(size_t)e6 * 32 + lane];
        unsigned int g7 = g2p[(size_t)e7 * 32 + lane];
        float2 f0 = up2(g0), f1 = up2(g1_), f2 = up2(g2), f3 = up2(g3);
        float2 f4 = up2(g4), f5 = up2(g5), f6 = up2(g6), f7 = up2(g7);
        ax0 += f0.x; ay0 += f0.y; ax1 += f1.x; ay1 += f1.y;
        ax2 += f2.x; ay2 += f2.y; ax3 += f3.x; ay3 += f3.y;
        ax0 += f4.x; ay0 += f4.y; ax1 += f5.x; ay1 += f5.y;
        ax2 += f6.x; ay2 += f6.y; ax3 += f7.x; ay3 += f7.y;
    }
    for (; j < t; ++j) {
        float2 f = up2(g2p[(size_t)ejn[j] * 32 + lane]);
        ax0 += f.x; ay0 += f.y;
    }
    float dv = rsqrtf((float)(cnt + 1));
    float ax = dv * ((ax0 + ax1) + (ax2 + ax3));
    float ay = dv * ((ay0 + ay1) + (ay2 + ay3));
    float m = fmaxf(ax, ay);
    #pragma unroll
    for (int off = 16; off >= 1; off >>= 1) m = fmaxf(m, __shfl_xor(m, off, 32));
    float sum = __expf(ax - m) + __expf(ay - m);
    #pragma unroll
    for (int off = 16; off >= 1; off >>= 1) sum += __shfl_xor(sum, off, 32);
    float lse = m + __logf(sum);
    float rx = ax - lse, ry = ay - lse;
    if (isbf) {
        ((unsigned int*)out)[(size_t)n * 32 + lane] = pk2(rx, ry);
    } else {
        float2* o = (float2*)((float*)out + (size_t)n * 64 + 2 * lane);
        *o = make_float2(rx, ry);
    }
}

extern "C" void kernel_launch(void* const* d_in, const int* in_sizes, int n_in,
                              void* d_out, int out_size, void* d_ws, size_t ws_size,
                              hipStream_t stream) {
    const void* x     = d_in[0];
    const void* W1    = d_in[1];
    const void* b1    = d_in[2];
    const void* gamma = d_in[3];
    const void* beta  = d_in[4];
    const void* W2    = d_in[5];
    const void* b2    = d_in[6];
    const void* ei    = d_in[7];

    char* w = (char*)d_ws;
    float*          stats  = (float*)(w + 0);                  //      1,024
    int*            gcnt   = (int*)(w + 1024);                 //        512 (98 used)
    int*            counts = (int*)(w + 2048);                 //    200,000 (zeroed in binA)
    int*            ej     = (int*)(w + 202048);               // 12,800,000 (N*SLOT*4)
    unsigned int*   bpk    = (unsigned int*)(w + 13002048);    //  3,411,968 (NBUK*BCAP*4)
    unsigned short* g1     = (unsigned short*)(w + 16414016);  // 12,800,000
    unsigned int*   agg1p  = (unsigned int*)(w + 29214016);    // 12,800,000
    unsigned short* g2     = (unsigned short*)(w + 42014016);  //  6,400,000
    // total ~48.4 MB

    hipMemsetAsync(w, 0, 2048, stream);   // stats + gcnt

    k_binA<<<(NE + EPB - 1) / EPB, 256, 0, stream>>>(ei, gcnt, counts, bpk);
    k_binB<<<NBUK * 4, 256, 0, stream>>>(bpk, gcnt, counts, ej);

    k_gemm1_mfma<<<(N_NODES + 63) / 64, 256, 0, stream>>>(x, W1, b1, counts, g1);

    k_prop1<<<2 * PHB, 256, 0, stream>>>(counts, ej, (const unsigned int*)g1, agg1p);

    k_stats<<<256, 256, 0, stream>>>((const unsigned int*)agg1p, stats);

    k_gemm2_mfma<<<(N_NODES + 63) / 64, 256, 0, stream>>>(agg1p, stats, gamma, beta, W2, b2,
                                                          W1, counts, g2);

    k_prop2_lsm<<<(N_NODES + 7) / 8, 256, 0, stream>>>(counts, ej, (const unsigned int*)g2, W1, d_out);
}

// Round 15
// 257.183 us; speedup vs baseline: 1.0712x; 1.0712x over previous
//
#include <hip/hip_runtime.h>
#include <hip/hip_bf16.h>

#define N_NODES 50000
#define NE      800000
#define DIN     128
#define DHID    128
#define DOUT    64
#define BN_EPS  1e-5f
#define SLOT    64      // padded CSR row capacity; P(Poisson(16)>64)~3e-18, guarded
#define NBUK    98      // dest buckets of 512 nodes (c>>9)
#define BCAP    8704    // bucket capacity: lambda=8163, +6 sigma, guarded
#define EPB     2048    // edges per block, binA
#define LDW     132     // padded W1T row (66 dwords, %32==2 -> <=2-way LDS aliasing)
#define LDW2    132

typedef __hip_bfloat16 bf16;
typedef short bf16x8 __attribute__((ext_vector_type(8)));
typedef float f32x4 __attribute__((ext_vector_type(4)));

__device__ __forceinline__ float ldf(const void* p, int i, int isbf) {
    if (isbf) return __bfloat162float(((const bf16*)p)[i]);
    return ((const float*)p)[i];
}
__device__ __forceinline__ unsigned short f2b(float f) {
    bf16 h = __float2bfloat16(f);
    return *(unsigned short*)&h;
}
__device__ __forceinline__ float2 up2(unsigned int u) {
    return make_float2(__uint_as_float(u << 16), __uint_as_float(u & 0xffff0000u));
}
__device__ __forceinline__ unsigned int pk2(float a, float b) {
    return ((unsigned int)f2b(a)) | (((unsigned int)f2b(b)) << 16);
}

#define DETECT_ISBF(W1raw, tid, sdet, isbf_out)                                   \
    if ((tid) == 0) sdet = 0;                                                     \
    __syncthreads();                                                              \
    {                                                                             \
        unsigned int u_ = ((unsigned int)((const unsigned short*)(W1raw))[tid]) << 16; \
        float f_ = fabsf(__uint_as_float(u_));                                    \
        if (!isnan(f_) && !isinf(f_) && f_ > 1e4f) atomicOr(&sdet, 1);            \
    }                                                                             \
    __syncthreads();                                                              \
    const int isbf_out = !sdet;

// ---------- binA: decode + LDS counting-sort by dest bucket + chunked coalesced write ----------
__global__ __launch_bounds__(256) void k_binA(const void* eiraw, int* __restrict__ gcnt,
                                              int* __restrict__ counts, unsigned int* __restrict__ bpk) {
    __shared__ int hist[128], lofs[128], cur[128], gbase[128];
    __shared__ unsigned int stg[EPB];
    __shared__ int sdet;
    int tid = threadIdx.x;
    for (int i = blockIdx.x * 256 + tid; i < N_NODES; i += gridDim.x * 256) counts[i] = 0;
    if (tid == 0) sdet = 0;
    if (tid < 128) hist[tid] = 0;
    __syncthreads();
    if (tid < 64 && ((const unsigned int*)eiraw)[2 * tid + 1] != 0u) atomicOr(&sdet, 1);
    __syncthreads();
    const int isll = !sdet;

    int e0 = blockIdx.x * EPB;
    int nE = NE - e0; if (nE > EPB) nE = EPB;
    int r[8], c[8];
    #pragma unroll
    for (int q = 0; q < 8; ++q) {
        int li = q * 256 + tid;
        if (li < nE) {
            int e = e0 + li;
            if (isll) { r[q] = (int)((const long long*)eiraw)[e]; c[q] = (int)((const long long*)eiraw)[NE + e]; }
            else      { r[q] = ((const int*)eiraw)[e];            c[q] = ((const int*)eiraw)[NE + e]; }
            atomicAdd(&hist[c[q] >> 9], 1);
        } else r[q] = -1;
    }
    __syncthreads();
    if (tid == 0) {
        int acc = 0;
        for (int b = 0; b < NBUK; ++b) { lofs[b] = acc; acc += hist[b]; }
    }
    __syncthreads();
    if (tid < NBUK) { gbase[tid] = atomicAdd(&gcnt[tid], hist[tid]); cur[tid] = lofs[tid]; }
    __syncthreads();
    #pragma unroll
    for (int q = 0; q < 8; ++q) {
        if (r[q] >= 0) {
            int b = c[q] >> 9;
            int p = atomicAdd(&cur[b], 1);
            stg[p] = ((unsigned int)b << 25) | ((unsigned int)(c[q] & 511) << 16) | (unsigned int)r[q];
        }
    }
    __syncthreads();
    for (int i = tid; i < nE; i += 256) {
        unsigned int v = stg[i];
        int b = v >> 25;
        int pos = gbase[b] + (i - lofs[b]);
        if (pos < BCAP) bpk[b * BCAP + pos] = v;
    }
}

// ---------- binB: per-bucket scatter into padded CSR, 4 blocks/bucket ----------
__global__ __launch_bounds__(256) void k_binB(const unsigned int* __restrict__ bpk, const int* __restrict__ gcnt,
                                              int* __restrict__ counts, int* __restrict__ ej) {
    int b = blockIdx.x >> 2;
    int part = blockIdx.x & 3;
    int m = gcnt[b]; if (m > BCAP) m = BCAP;
    const unsigned int* src = bpk + b * BCAP;
    for (int i = part * 256 + threadIdx.x; i < m; i += 1024) {
        unsigned int v = src[i];
        int c = (b << 9) | ((v >> 16) & 511);
        int s = v & 0xffff;
        int k = atomicAdd(&counts[c], 1);
        if (k < SLOT) ej[c * SLOT + k] = s;
    }
}

// ---------- GEMM1 (MFMA): g1 = bf16(dis[m] * (x @ W1 + b1)), dis from counts ----------
__global__ __launch_bounds__(256) void k_gemm1_mfma(const void* __restrict__ x, const void* __restrict__ W1,
                                                    const void* __restrict__ b1, const int* __restrict__ counts,
                                                    unsigned short* __restrict__ g1) {
    __shared__ unsigned short wt[128 * LDW];
    __shared__ int sdet;
    int tid = threadIdx.x;
    DETECT_ISBF(W1, tid, sdet, isbf)

    #pragma unroll 4
    for (int i = 0; i < 64; ++i) {
        int idx = i * 256 + tid;
        int k = idx >> 7, n = idx & 127;
        wt[n * LDW + k] = isbf ? ((const unsigned short*)W1)[idx]
                               : f2b(((const float*)W1)[idx]);
    }
    __syncthreads();

    int lane = tid & 63;
    int wave = tid >> 6;
    int m0 = blockIdx.x * 64 + wave * 16;
    int lm = lane & 15;
    int quad = lane >> 4;

    bf16x8 a[4];
    int arow = m0 + lm;
    int arow_c = arow < N_NODES ? arow : 0;
    if (isbf) {
        const unsigned short* xb = (const unsigned short*)x;
        #pragma unroll
        for (int q = 0; q < 4; ++q)
            a[q] = *(const bf16x8*)(xb + arow_c * DIN + q * 32 + quad * 8);
    } else {
        const float* xf = (const float*)x;
        #pragma unroll
        for (int q = 0; q < 4; ++q) {
            bf16x8 t;
            #pragma unroll
            for (int j = 0; j < 8; ++j)
                t[j] = (short)f2b(xf[arow_c * DIN + q * 32 + quad * 8 + j]);
            a[q] = t;
        }
    }

    float dsc[4];
    #pragma unroll
    for (int r = 0; r < 4; ++r) {
        int grow = m0 + quad * 4 + r;
        dsc[r] = (grow < N_NODES) ? rsqrtf((float)(counts[grow] + 1)) : 0.f;
    }

    #pragma unroll
    for (int nt = 0; nt < 8; ++nt) {
        int n0 = nt * 16;
        f32x4 acc = {0.f, 0.f, 0.f, 0.f};
        #pragma unroll
        for (int q = 0; q < 4; ++q) {
            bf16x8 b = *(const bf16x8*)(wt + (n0 + lm) * LDW + q * 32 + quad * 8);
            acc = __builtin_amdgcn_mfma_f32_16x16x32_bf16(a[q], b, acc, 0, 0, 0);
        }
        float bias = ldf(b1, n0 + lm, isbf);
        #pragma unroll
        for (int r = 0; r < 4; ++r) {
            int grow = m0 + quad * 4 + r;
            if (grow < N_NODES)
                g1[grow * DHID + n0 + lm] = f2b(dsc[r] * (acc[r] + bias));
        }
    }
}

// ---------- propagate 1 (R12 form): agg1[c] = bf16( dis[c] * (g1[c] + sum g1[src]) ) ----------
__global__ __launch_bounds__(256) void k_prop1(const int* __restrict__ counts, const int* __restrict__ ej,
                                               const unsigned int* __restrict__ g1p,   // [N][64] dwords
                                               unsigned int* __restrict__ agg1p) {
    int tid = threadIdx.x;
    int n = blockIdx.x * 4 + (tid >> 6);
    n = __builtin_amdgcn_readfirstlane(n);   // wave-uniform: scalarize edge addressing
    if (n >= N_NODES) return;
    int lane = tid & 63;
    int cnt = counts[n];
    int t = cnt < SLOT ? cnt : SLOT;
    const int* ejn = ej + (size_t)n * SLOT;
    float2 v = up2(g1p[(size_t)n * 64 + lane]);
    float ax0 = v.x, ay0 = v.y, ax1 = 0.f, ay1 = 0.f;
    float ax2 = 0.f, ay2 = 0.f, ax3 = 0.f, ay3 = 0.f;
    int j = 0;
    for (; j + 8 <= t; j += 8) {
        int e0 = ejn[j], e1 = ejn[j + 1], e2 = ejn[j + 2], e3 = ejn[j + 3];
        int e4 = ejn[j + 4], e5 = ejn[j + 5], e6 = ejn[j + 6], e7 = ejn[j + 7];
        unsigned int g0 = g1p[(size_t)e0 * 64 + lane];
        unsigned int g1_ = g1p[(size_t)e1 * 64 + lane];
        unsigned int g2 = g1p[(size_t)e2 * 64 + lane];
        unsigned int g3 = g1p[(size_t)e3 * 64 + lane];
        unsigned int g4 = g1p[(size_t)e4 * 64 + lane];
        unsigned int g5 = g1p[(size_t)e5 * 64 + lane];
        unsigned int g6 = g1p[(size_t)e6 * 64 + lane];
        unsigned int g7 = g1p[(size_t)e7 * 64 + lane];
        float2 f0 = up2(g0), f1 = up2(g1_), f2 = up2(g2), f3 = up2(g3);
        float2 f4 = up2(g4), f5 = up2(g5), f6 = up2(g6), f7 = up2(g7);
        ax0 += f0.x; ay0 += f0.y; ax1 += f1.x; ay1 += f1.y;
        ax2 += f2.x; ay2 += f2.y; ax3 += f3.x; ay3 += f3.y;
        ax0 += f4.x; ay0 += f4.y; ax1 += f5.x; ay1 += f5.y;
        ax2 += f6.x; ay2 += f6.y; ax3 += f7.x; ay3 += f7.y;
    }
    for (; j < t; ++j) {
        float2 f = up2(g1p[(size_t)ejn[j] * 64 + lane]);
        ax0 += f.x; ay0 += f.y;
    }
    float dv = rsqrtf((float)(cnt + 1));
    float ax = dv * ((ax0 + ax1) + (ax2 + ax3));
    float ay = dv * ((ay0 + ay1) + (ay2 + ay3));
    agg1p[(size_t)n * 64 + lane] = pk2(ax, ay);
}

// ---------- BN statistics over bf16 agg1 ----------
__global__ __launch_bounds__(256) void k_stats(const unsigned int* __restrict__ agg1p, float* __restrict__ stats) {
    int tid = threadIdx.x;
    const int total = N_NODES * 64;
    float sx = 0.f, sy = 0.f, qx = 0.f, qy = 0.f;
    for (int idx = blockIdx.x * 256 + tid; idx < total; idx += gridDim.x * 256) {
        float2 v = up2(agg1p[idx]);
        sx += v.x; sy += v.y; qx += v.x * v.x; qy += v.y * v.y;
    }
    __shared__ float lsx[256], lsy[256], lqx[256], lqy[256];
    lsx[tid] = sx; lsy[tid] = sy; lqx[tid] = qx; lqy[tid] = qy;
    __syncthreads();
    if (tid < 64) {
        float tsx = lsx[tid] + lsx[tid + 64] + lsx[tid + 128] + lsx[tid + 192];
        float tsy = lsy[tid] + lsy[tid + 64] + lsy[tid + 128] + lsy[tid + 192];
        float tqx = lqx[tid] + lqx[tid + 64] + lqx[tid + 128] + lqx[tid + 192];
        float tqy = lqy[tid] + lqy[tid + 64] + lqy[tid + 128] + lqy[tid + 192];
        atomicAdd(&stats[2 * tid], tsx);
        atomicAdd(&stats[2 * tid + 1], tsy);
        atomicAdd(&stats[128 + 2 * tid], tqx);
        atomicAdd(&stats[128 + 2 * tid + 1], tqy);
    }
}

// ---------- GEMM2 (MFMA), BN finalize in preamble, BN+ReLU on A, dis-scale out ----------
__global__ __launch_bounds__(256) void k_gemm2_mfma(const unsigned int* __restrict__ agg1p,
                                                    const float* __restrict__ stats,
                                                    const void* __restrict__ gamma, const void* __restrict__ beta,
                                                    const void* __restrict__ W2, const void* __restrict__ b2,
                                                    const void* __restrict__ W1, const int* __restrict__ counts,
                                                    unsigned short* __restrict__ g2) {
    __shared__ unsigned short w2t[64 * LDW2];
    __shared__ float sc[128], sh[128];
    __shared__ int sdet;
    int tid = threadIdx.x;
    DETECT_ISBF(W1, tid, sdet, isbf)

    #pragma unroll 4
    for (int i = 0; i < 32; ++i) {
        int idx = i * 256 + tid;
        int k = idx >> 6, n = idx & 63;
        w2t[n * LDW2 + k] = isbf ? ((const unsigned short*)W2)[idx]
                                 : f2b(((const float*)W2)[idx]);
    }
    if (tid < 128) {
        const float invn = 1.0f / (float)N_NODES;
        float mu = stats[tid] * invn;
        float var = stats[128 + tid] * invn - mu * mu;
        float rs = rsqrtf(var + BN_EPS);
        float g = ldf(gamma, tid, isbf);
        sc[tid] = rs * g;
        sh[tid] = ldf(beta, tid, isbf) - mu * rs * g;
    }
    __syncthreads();

    int lane = tid & 63;
    int wave = tid >> 6;
    int m0 = blockIdx.x * 64 + wave * 16;
    int lm = lane & 15;
    int quad = lane >> 4;

    int arow = m0 + lm;
    int arow_c = arow < N_NODES ? arow : 0;
    bf16x8 a[4];
    #pragma unroll
    for (int q = 0; q < 4; ++q) {
        uint4 gv = *(const uint4*)(agg1p + (size_t)arow_c * 64 + q * 16 + quad * 4);
        int kb = q * 32 + quad * 8;
        float2 f0 = up2(gv.x), f1 = up2(gv.y), f2 = up2(gv.z), f3 = up2(gv.w);
        float e0 = f0.x * sc[kb + 0] + sh[kb + 0];
        float e1 = f0.y * sc[kb + 1] + sh[kb + 1];
        float e2 = f1.x * sc[kb + 2] + sh[kb + 2];
        float e3 = f1.y * sc[kb + 3] + sh[kb + 3];
        float e4 = f2.x * sc[kb + 4] + sh[kb + 4];
        float e5 = f2.y * sc[kb + 5] + sh[kb + 5];
        float e6 = f3.x * sc[kb + 6] + sh[kb + 6];
        float e7 = f3.y * sc[kb + 7] + sh[kb + 7];
        bf16x8 t;
        t[0] = (short)f2b(e0 > 0.f ? e0 : 0.f);
        t[1] = (short)f2b(e1 > 0.f ? e1 : 0.f);
        t[2] = (short)f2b(e2 > 0.f ? e2 : 0.f);
        t[3] = (short)f2b(e3 > 0.f ? e3 : 0.f);
        t[4] = (short)f2b(e4 > 0.f ? e4 : 0.f);
        t[5] = (short)f2b(e5 > 0.f ? e5 : 0.f);
        t[6] = (short)f2b(e6 > 0.f ? e6 : 0.f);
        t[7] = (short)f2b(e7 > 0.f ? e7 : 0.f);
        a[q] = t;
    }

    float dsc[4];
    #pragma unroll
    for (int r = 0; r < 4; ++r) {
        int grow = m0 + quad * 4 + r;
        dsc[r] = (grow < N_NODES) ? rsqrtf((float)(counts[grow] + 1)) : 0.f;
    }

    #pragma unroll
    for (int nt = 0; nt < 4; ++nt) {
        int n0 = nt * 16;
        f32x4 acc = {0.f, 0.f, 0.f, 0.f};
        #pragma unroll
        for (int q = 0; q < 4; ++q) {
            bf16x8 b = *(const bf16x8*)(w2t + (n0 + lm) * LDW2 + q * 32 + quad * 8);
            acc = __builtin_amdgcn_mfma_f32_16x16x32_bf16(a[q], b, acc, 0, 0, 0);
        }
        float bias = ldf(b2, n0 + lm, isbf);
        #pragma unroll
        for (int r = 0; r < 4; ++r) {
            int grow = m0 + quad * 4 + r;
            if (grow < N_NODES)
                g2[grow * DOUT + n0 + lm] = f2b(dsc[r] * (acc[r] + bias));
        }
    }
}

// ---------- propagate 2 + log_softmax: 32 lanes/node, 2 feats/lane, 16-edge ILP ----------
__global__ __launch_bounds__(256) void k_prop2_lsm(const int* __restrict__ counts, const int* __restrict__ ej,
                                                   const unsigned int* __restrict__ g2p,   // [N][32] dwords
                                                   const void* __restrict__ W1, void* __restrict__ out) {
    __shared__ int sdet;
    int tid = threadIdx.x;
    DETECT_ISBF(W1, tid, sdet, isbf)

    int n = blockIdx.x * 8 + (tid >> 5);
    if (n >= N_NODES) return;
    int lane = tid & 31;
    int cnt = counts[n];
    int t = cnt < SLOT ? cnt : SLOT;
    const int* ejn = ej + (size_t)n * SLOT;
    float2 v = up2(g2p[(size_t)n * 32 + lane]);
    float ax0 = v.x, ay0 = v.y, ax1 = 0.f, ay1 = 0.f;
    float ax2 = 0.f, ay2 = 0.f, ax3 = 0.f, ay3 = 0.f;
    int j = 0;
    for (; j + 16 <= t; j += 16) {
        int e[16]; unsigned int gg[16];
        #pragma unroll
        for (int q = 0; q < 16; ++q) e[q] = ejn[j + q];
        #pragma unroll
        for (int q = 0; q < 16; ++q) gg[q] = g2p[(size_t)e[q] * 32 + lane];
        #pragma unroll
        for (int q = 0; q < 16; ++q) {
            float2 f = up2(gg[q]);
            if ((q & 3) == 0) { ax0 += f.x; ay0 += f.y; }
            else if ((q & 3) == 1) { ax1 += f.x; ay1 += f.y; }
            else if ((q & 3) == 2) { ax2 += f.x; ay2 += f.y; }
            else { ax3 += f.x; ay3 += f.y; }
        }
    }
    for (; j + 4 <= t; j += 4) {
        int e0 = ejn[j], e1 = ejn[j + 1], e2 = ejn[j + 2], e3 = ejn[j + 3];
        unsigned int g0 = g2p[(size_t)e0 * 32 + lane];
        unsigned int g1_ = g2p[(size_t)e1 * 32 + lane];
        unsigned int g2 = g2p[(size_t)e2 * 32 + lane];
        unsigned int g3 = g2p[(size_t)e3 * 32 + lane];
        float2 f0 = up2(g0), f1 = up2(g1_), f2 = up2(g2), f3 = up2(g3);
        ax0 += f0.x; ay0 += f0.y; ax1 += f1.x; ay1 += f1.y;
        ax2 += f2.x; ay2 += f2.y; ax3 += f3.x; ay3 += f3.y;
    }
    for (; j < t; ++j) {
        float2 f = up2(g2p[(size_t)ejn[j] * 32 + lane]);
        ax0 += f.x; ay0 += f.y;
    }
    float dv = rsqrtf((float)(cnt + 1));
    float ax = dv * ((ax0 + ax1) + (ax2 + ax3));
    float ay = dv * ((ay0 + ay1) + (ay2 + ay3));
    float m = fmaxf(ax, ay);
    #pragma unroll
    for (int off = 16; off >= 1; off >>= 1) m = fmaxf(m, __shfl_xor(m, off, 32));
    float sum = __expf(ax - m) + __expf(ay - m);
    #pragma unroll
    for (int off = 16; off >= 1; off >>= 1) sum += __shfl_xor(sum, off, 32);
    float lse = m + __logf(sum);
    float rx = ax - lse, ry = ay - lse;
    if (isbf) {
        ((unsigned int*)out)[(size_t)n * 32 + lane] = pk2(rx, ry);
    } else {
        float2* o = (float2*)((float*)out + (size_t)n * 64 + 2 * lane);
        *o = make_float2(rx, ry);
    }
}

extern "C" void kernel_launch(void* const* d_in, const int* in_sizes, int n_in,
                              void* d_out, int out_size, void* d_ws, size_t ws_size,
                              hipStream_t stream) {
    const void* x     = d_in[0];
    const void* W1    = d_in[1];
    const void* b1    = d_in[2];
    const void* gamma = d_in[3];
    const void* beta  = d_in[4];
    const void* W2    = d_in[5];
    const void* b2    = d_in[6];
    const void* ei    = d_in[7];

    char* w = (char*)d_ws;
    float*          stats  = (float*)(w + 0);                  //      1,024
    int*            gcnt   = (int*)(w + 1024);                 //        512 (98 used)
    int*            counts = (int*)(w + 2048);                 //    200,000 (zeroed in binA)
    int*            ej     = (int*)(w + 202048);               // 12,800,000 (N*SLOT*4)
    unsigned int*   bpk    = (unsigned int*)(w + 13002048);    //  3,411,968 (NBUK*BCAP*4)
    unsigned short* g1     = (unsigned short*)(w + 16414016);  // 12,800,000
    unsigned int*   agg1p  = (unsigned int*)(w + 29214016);    // 12,800,000
    unsigned short* g2     = (unsigned short*)(w + 42014016);  //  6,400,000
    // total ~48.4 MB

    hipMemsetAsync(w, 0, 2048, stream);   // stats + gcnt

    k_binA<<<(NE + EPB - 1) / EPB, 256, 0, stream>>>(ei, gcnt, counts, bpk);
    k_binB<<<NBUK * 4, 256, 0, stream>>>(bpk, gcnt, counts, ej);

    k_gemm1_mfma<<<(N_NODES + 63) / 64, 256, 0, stream>>>(x, W1, b1, counts, g1);

    k_prop1<<<(N_NODES + 3) / 4, 256, 0, stream>>>(counts, ej, (const unsigned int*)g1, agg1p);

    k_stats<<<256, 256, 0, stream>>>((const unsigned int*)agg1p, stats);

    k_gemm2_mfma<<<(N_NODES + 63) / 64, 256, 0, stream>>>(agg1p, stats, gamma, beta, W2, b2,
                                                          W1, counts, g2);

    k_prop2_lsm<<<(N_NODES + 7) / 8, 256, 0, stream>>>(counts, ej, (const unsigned int*)g2, W1, d_out);
}